// Round 7
// baseline (257.388 us; speedup 1.0000x reference)
//
#include <hip/hip_runtime.h>
#include <math.h>

#define TT 1536
#define CC 1536
#define NH 8
#define KD 64
#define VD 192
#define FD 192

typedef short bf16x8 __attribute__((ext_vector_type(8)));
typedef float f32x4 __attribute__((ext_vector_type(4)));

__device__ inline unsigned short f2bf(float x) {
    unsigned u = __float_as_uint(x);
    u += 0x7FFF + ((u >> 16) & 1);
    return (unsigned short)(u >> 16);
}
__device__ inline float bf2f(unsigned short b) {
    return __uint_as_float(((unsigned)b) << 16);
}
__device__ inline void gload16(const void* g, void* l) {
    __builtin_amdgcn_global_load_lds(
        (const __attribute__((address_space(1))) unsigned int*)g,
        (__attribute__((address_space(3))) unsigned int*)l, 16, 0, 0);
}
// 16B-chunk XOR swizzle within a 64-elem (128B) bf16 row: chunk' = chunk ^ (row&7)
__device__ inline int swzo(int row, int chunk) { return (chunk ^ (row & 7)) << 3; }

template<int N> __device__ inline void vmwait() {
    if constexpr (N == 0)      asm volatile("s_waitcnt vmcnt(0)" ::: "memory");
    else if constexpr (N == 4) asm volatile("s_waitcnt vmcnt(4)" ::: "memory");
    else if constexpr (N == 6) asm volatile("s_waitcnt vmcnt(6)" ::: "memory");
    else                       asm volatile("s_waitcnt vmcnt(8)" ::: "memory");
}
__device__ inline void lgkmwait0() {
    asm volatile("s_waitcnt lgkmcnt(0)" ::: "memory");
}

// ---------------- wave-per-row LayerNorm helper (f32 -> bf16) ----------------
__device__ inline void ln_row(const float* __restrict__ x,
                              const float* __restrict__ g,
                              const float* __restrict__ b,
                              unsigned short* __restrict__ out,
                              int row, int lane)
{
    const float* xr = x + (size_t)row * CC;
    unsigned short* orow = out + (size_t)row * CC;

    float4 V[6];
    float s = 0.f, ss = 0.f;
#pragma unroll
    for (int c = 0; c < 6; c++) {
        V[c] = *reinterpret_cast<const float4*>(&xr[c * 256 + lane * 4]);
        s  += V[c].x + V[c].y + V[c].z + V[c].w;
        ss += V[c].x * V[c].x + V[c].y * V[c].y + V[c].z * V[c].z + V[c].w * V[c].w;
    }
#pragma unroll
    for (int off = 32; off; off >>= 1) {
        s  += __shfl_xor(s, off);
        ss += __shfl_xor(ss, off);
    }
    float mean = s * (1.f / CC);
    float var  = ss * (1.f / CC) - mean * mean;
    float rstd = rsqrtf(fmaxf(var, 0.f) + 1e-3f);
#pragma unroll
    for (int c = 0; c < 6; c++) {
        float4 G = *reinterpret_cast<const float4*>(&g[c * 256 + lane * 4]);
        float4 B = *reinterpret_cast<const float4*>(&b[c * 256 + lane * 4]);
        ushort4 pk;
        pk.x = f2bf((V[c].x - mean) * rstd * G.x + B.x);
        pk.y = f2bf((V[c].y - mean) * rstd * G.y + B.y);
        pk.z = f2bf((V[c].z - mean) * rstd * G.z + B.z);
        pk.w = f2bf((V[c].w - mean) * rstd * G.w + B.w);
        *reinterpret_cast<ushort4*>(&orow[c * 256 + lane * 4]) = pk;
    }
}

// standalone ln (4 rows per block, 1 wave per row)
__global__ __launch_bounds__(256)
void ln_kernel(const float* __restrict__ x, const float* __restrict__ g,
               const float* __restrict__ b, unsigned short* __restrict__ out)
{
    int wid = threadIdx.x >> 6, lane = threadIdx.x & 63;
    ln_row(x, g, b, out, blockIdx.x * 4 + wid, lane);
}

// ---------------- merged prep: weight convert (7 mats) + ln1 + pos -----------
struct WCD { const float* W; unsigned short* Wt; int Kw, Nw, t0; };
struct WCP { WCD e[7]; };
#define WCONV_BLKS 15456
#define LN1_BLKS   384
#define POS_BLKS   (2 * TT - 1)

__global__ __launch_bounds__(256)
void prep_all(WCP p, const float* __restrict__ x,
              const float* __restrict__ ln1_g, const float* __restrict__ ln1_b,
              unsigned short* __restrict__ xnb, unsigned short* __restrict__ pos)
{
    int bid = blockIdx.x;
    int tid = threadIdx.x;

    if (bid < WCONV_BLKS) {
        __shared__ float t[32][33];
        int i = 0;
#pragma unroll
        for (int j = 1; j < 7; j++) if (bid >= p.e[j].t0) i = j;
        const float* W = p.e[i].W;
        unsigned short* Wt = p.e[i].Wt;
        int Kw = p.e[i].Kw, Nw = p.e[i].Nw;
        int local = bid - p.e[i].t0;
        int tpx = Nw >> 5;
        int n0 = (local % tpx) * 32, k0 = (local / tpx) * 32;

        int r = tid >> 3, c4 = (tid & 7) * 4;
        float4 v = *reinterpret_cast<const float4*>(&W[(size_t)(k0 + r) * Nw + n0 + c4]);
        t[r][c4 + 0] = v.x; t[r][c4 + 1] = v.y; t[r][c4 + 2] = v.z; t[r][c4 + 3] = v.w;
        __syncthreads();
        ushort4 pk;
        pk.x = f2bf(t[c4 + 0][r]);
        pk.y = f2bf(t[c4 + 1][r]);
        pk.z = f2bf(t[c4 + 2][r]);
        pk.w = f2bf(t[c4 + 3][r]);
        *reinterpret_cast<ushort4*>(&Wt[(size_t)(n0 + r) * Kw + k0 + c4]) = pk;
        return;
    }

    if (bid < WCONV_BLKS + LN1_BLKS) {
        int grp = bid - WCONV_BLKS;
        int wid = tid >> 6, lane = tid & 63;
        ln_row(x, ln1_g, ln1_b, xnb, grp * 4 + wid, lane);
        return;
    }

    // positional features, one l per block
    {
        int l = bid - (WCONV_BLKS + LN1_BLKS);
        float pp = (float)(l - (TT - 1));
        float ap = fabsf(pp);
        float sgn = (pp > 0.f) ? 1.f : ((pp < 0.f) ? -1.f : 0.f);

        __shared__ float gp[32];
        __shared__ float gmax_s;
        if (tid < 32) {
            int j = tid;
            double conc = 4.0 * (double)(j + 1) * (double)(j + 1);
            double rate = (double)(j + 1) / 12.0;
            double log_norm = lgamma(conc) - conc * log(rate);
            double prob;
            if (ap == 0.f) prob = 1e-8;
            else prob = exp((conc - 1.0) * log((double)ap) - rate * (double)ap - log_norm) + 1e-8;
            gp[j] = (float)prob;
        }
        __syncthreads();
        if (tid == 0) {
            float m = gp[0];
            for (int j = 1; j < 32; j++) m = fmaxf(m, gp[j]);
            gmax_s = m;
        }
        __syncthreads();
        if (tid < 96) {
            int cls = tid / 32, j = tid % 32;
            float val;
            if (cls == 0) {
                double step = (10.584962500721156 - 3.0) / 31.0;
                double hl = exp2(3.0 + j * step);
                val = (float)exp(-(double)ap * 0.6931471805599453 / hl);
            } else if (cls == 1) {
                float width = exp2f((float)(j + 1)) - 1.f;
                val = (width > ap) ? 1.f : 0.f;
            } else {
                val = gp[j] / gmax_s;
            }
            pos[(size_t)l * FD + tid] = f2bf(val);
            pos[(size_t)l * FD + 96 + tid] = f2bf(sgn * val);
        }
    }
}

// ---------------- bf16 MFMA GEMM, TMxTN tile, 4 waves ----------------
// 2-deep double buffer + counted vmcnt. Wave tile = (TM/2)x(TN/2).
// xm: 2 or 4 -> 2D XCD chunking; 0 -> linear XCD swizzle.
// mode 0: f32 out  mode 1: bf16 out  mode 4: fused qkv epilogue
// head_ndiv!=0: A += (n0/head_ndiv)*sA
template<int TM, int TN>
__global__ __launch_bounds__(256)
void gemm_bf16(const unsigned short* __restrict__ A,
               const unsigned short* __restrict__ Bt,
               void* __restrict__ Cv, unsigned short* __restrict__ C2,
               unsigned short* __restrict__ C3,
               int M, int N, int K, int lda, int ldb, int ldc,
               long sA, long sB, long sC,
               float alpha, const float* __restrict__ bias,
               const float* __restrict__ bias2,
               const float* __restrict__ resid,
               int mode, int relu, int head_ndiv, int xm)
{
    constexpr int WM = TM / 2, WN = TN / 2;
    constexpr int MF = WM / 16, NF = WN / 16;
    constexpr int LPT = TM / 32 + TN / 32;       // per-thread loads per K-tile
    __shared__ unsigned short lA[2][TM * 64];
    __shared__ unsigned short lB[2][TN * 64];

    int tid = threadIdx.x;
    int w = tid >> 6, l = tid & 63;

    // block -> (bx, by) mapping
    int gx = gridDim.x, gy = gridDim.y;
    int d = blockIdx.y * gx + blockIdx.x;
    int bx, by;
    if (xm) {
        int xn = 8 / xm;
        int cm = gy / xm, cn = gx / xn;
        int xcd = d & 7, local = d >> 3;
        int bxl = local / cm, byl = local % cm;
        by = (xcd / xn) * cm + byl;
        bx = (xcd % xn) * cn + bxl;
    } else {
        int nwg = gx * gy;
        int work = d;
        if ((nwg & 7) == 0) work = (d & 7) * (nwg >> 3) + (d >> 3);
        bx = work % gx;
        by = work / gx;
    }

    int n0 = bx * TN;
    int m0 = by * TM;
    if (head_ndiv) {
        A += (size_t)(n0 / head_ndiv) * sA;
    } else {
        A  += (size_t)blockIdx.z * sA;
        Bt += (size_t)blockIdx.z * sB;
    }
    int R0 = (w & 1) * WM, C0 = (w >> 1) * WN;
    int lrow = l >> 3;
    int lsw = ((l & 7) ^ lrow) << 3;       // swizzled source chunk (elements)
    int l15 = l & 15, lg = l >> 4;

    f32x4 acc[MF][NF] = {};

    const int NSTEP = K >> 6;

    auto STAGE = [&](int t, int buf) {
        int k0 = t << 6;
#pragma unroll
        for (int q = 0; q < TM / 32; q++) {
            int r0 = w * (TM / 4) + q * 8;
            gload16(A + (size_t)(m0 + r0 + lrow) * lda + k0 + lsw, &lA[buf][r0 * 64]);
        }
#pragma unroll
        for (int q = 0; q < TN / 32; q++) {
            int r0 = w * (TN / 4) + q * 8;
            gload16(Bt + (size_t)(n0 + r0 + lrow) * ldb + k0 + lsw, &lB[buf][r0 * 64]);
        }
    };

    STAGE(0, 0);

    int cur = 0;
    for (int t = 0; t < NSTEP; ++t) {
        if (t + 1 < NSTEP) {
            STAGE(t + 1, cur ^ 1);     // buffer freed by barrier at end of t-1
            vmwait<LPT>();             // tile t complete; t+1 stays in flight
        } else {
            vmwait<0>();
        }
        __builtin_amdgcn_s_barrier();
        __builtin_amdgcn_sched_barrier(0);

#pragma unroll
        for (int kk = 0; kk < 2; kk++) {
            int ch = kk * 4 + lg;
            bf16x8 av[MF], bv[NF];
#pragma unroll
            for (int m = 0; m < MF; m++) {
                int row = R0 + m * 16 + l15;
                av[m] = *(const bf16x8*)&lA[cur][row * 64 + swzo(row, ch)];
            }
#pragma unroll
            for (int n = 0; n < NF; n++) {
                int row = C0 + n * 16 + l15;
                bv[n] = *(const bf16x8*)&lB[cur][row * 64 + swzo(row, ch)];
            }
#pragma unroll
            for (int m = 0; m < MF; m++)
#pragma unroll
                for (int n = 0; n < NF; n++)
                    acc[m][n] = __builtin_amdgcn_mfma_f32_16x16x32_bf16(av[m], bv[n], acc[m][n], 0, 0, 0);
        }
        __builtin_amdgcn_s_barrier();  // all waves done reading buf cur
        cur ^= 1;
    }

    int rb = m0 + R0 + lg * 4;
    int cb = n0 + C0 + l15;

    if (mode == 4) {
        unsigned short* qw = (unsigned short*)Cv;
#pragma unroll
        for (int m = 0; m < MF; m++) {
            int rowb = rb + m * 16;
#pragma unroll
            for (int n = 0; n < NF; n++) {
                int col = cb + n * 16;
                if (col < 512) {
#pragma unroll
                    for (int reg = 0; reg < 4; reg++) {
                        int row = rowb + reg;
                        float v = alpha * acc[m][n][reg];
                        qw[(size_t)row * 512 + col] = f2bf(v + bias[col]);
                        C2[(size_t)row * 512 + col] = f2bf(v + bias2[col]);
                    }
                } else if (col < 1024) {
                    unsigned short* kb = C3;
#pragma unroll
                    for (int reg = 0; reg < 4; reg++)
                        kb[(size_t)(rowb + reg) * 512 + col - 512] = f2bf(acc[m][n][reg]);
                } else {
                    unsigned short* vT = (unsigned short*)(void*)(C3 + (size_t)1536 * 512);
                    int vc = col - 1024;
                    ushort4 pk;
                    pk.x = f2bf(acc[m][n][0]);
                    pk.y = f2bf(acc[m][n][1]);
                    pk.z = f2bf(acc[m][n][2]);
                    pk.w = f2bf(acc[m][n][3]);
                    *reinterpret_cast<ushort4*>(&vT[(size_t)vc * 1536 + rowb]) = pk;
                }
            }
        }
        return;
    }

#pragma unroll
    for (int m = 0; m < MF; m++) {
#pragma unroll
        for (int n = 0; n < NF; n++) {
            int col = cb + n * 16;
            if (col >= N) continue;
            float bs = bias ? bias[col] : 0.f;
#pragma unroll
            for (int reg = 0; reg < 4; reg++) {
                int row = rb + m * 16 + reg;
                if (row >= M) continue;
                float v = alpha * acc[m][n][reg] + bs;
                if (resid) v += resid[(size_t)row * ldc + col];
                if (relu)  v = fmaxf(v, 0.f);
                if (mode == 1) {
                    unsigned short* C = (unsigned short*)Cv + (size_t)blockIdx.z * sC;
                    C[(size_t)row * ldc + col] = f2bf(v);
                } else {
                    float* C = (float*)Cv + (size_t)blockIdx.z * sC;
                    C[(size_t)row * ldc + col] = v;
                }
            }
        }
    }
}

// ---------------- flash attention: logits + softmax + PV fused ----------------
// per block: head h, 32 Q-rows. 4 waves. 24 j-steps of 64 keys.
// LDS 64KB: Q(8K, aliased by P+red after prolog) K(8K) RK(16K) V(24K) R(8K)
// K/RK prefetched 1 step ahead behind counted vmcnt(6); V staged at step top.
#define AOF_QW 0
#define AOF_QR 2048
#define AOF_P  0
#define AOF_RED 2048
#define AOF_K  4096
#define AOF_RK 8192
#define AOF_V  16384
#define AOF_R  28672

__global__ __launch_bounds__(256)
void attn_flash(const unsigned short* __restrict__ qw,
                const unsigned short* __restrict__ qr,
                const unsigned short* __restrict__ kmat,
                const unsigned short* __restrict__ rkb,
                const unsigned short* __restrict__ vT,
                unsigned short* __restrict__ ob)
{
    __shared__ unsigned short pool[32768];
    int i0 = blockIdx.x * 32;
    int h  = blockIdx.y;
    int tid = threadIdx.x;
    int w = tid >> 6, l = tid & 63;
    int lrow = l >> 3;
    int lsw = ((l & 7) ^ lrow) << 3;
    int l15 = l & 15, lg = l >> 4;

    auto stageK = [&](int j0) {
#pragma unroll
        for (int q = 0; q < 2; q++) {
            int r0 = w * 16 + q * 8;
            gload16(kmat + (size_t)(j0 + r0 + lrow) * 512 + h * KD + lsw, &pool[AOF_K + r0 * 64]);
        }
    };
    auto stageRK = [&](int j0) {
        int ob32 = j0 - i0 + 1504;   // band row b -> rk row ob32+b ; used b = 31+v-u in [0,94]
#pragma unroll
        for (int q = 0; q < 4; q++) {
            int r0 = w * 32 + q * 8;
            gload16(rkb + (size_t)(ob32 + r0 + lrow) * 512 + h * KD + lsw, &pool[AOF_RK + r0 * 64]);
        }
    };
    auto stageV = [&](int j0) {
#pragma unroll
        for (int q = 0; q < 6; q++) {
            int r0 = w * 48 + q * 8;
            gload16(vT + (size_t)(h * VD + r0 + lrow) * 1536 + j0 + lsw, &pool[AOF_V + r0 * 64]);
        }
    };

    // prolog: Q tiles + K/RK for j=0
    gload16(qw + (size_t)(i0 + w * 8 + lrow) * 512 + h * KD + lsw, &pool[AOF_QW + (w * 8) * 64]);
    gload16(qr + (size_t)(i0 + w * 8 + lrow) * 512 + h * KD + lsw, &pool[AOF_QR + (w * 8) * 64]);
    stageK(0); stageRK(0);
    vmwait<0>();
    __builtin_amdgcn_s_barrier();
    __builtin_amdgcn_sched_barrier(0);

    bf16x8 qwf[2][2], qrf[2][2];    // [m-frag][kk]
#pragma unroll
    for (int m = 0; m < 2; m++)
#pragma unroll
        for (int kk = 0; kk < 2; kk++) {
            int row = m * 16 + l15;
            qwf[m][kk] = *(const bf16x8*)&pool[AOF_QW + row * 64 + swzo(row, kk * 4 + lg)];
            qrf[m][kk] = *(const bf16x8*)&pool[AOF_QR + row * 64 + swzo(row, kk * 4 + lg)];
        }
    lgkmwait0();                    // Q reads done before the area is aliased

    f32x4 accO[2][3] = {};
    float m_run[2][4], l_run[2][4];
#pragma unroll
    for (int m = 0; m < 2; m++)
#pragma unroll
        for (int r = 0; r < 4; r++) { m_run[m][r] = -3e38f; l_run[m][r] = 0.f; }

    float* redm = (float*)&pool[AOF_RED];   // [32][4] partial max
    float* reds = redm + 128;               // [32][4] partial sum
    unsigned short* Rl = &pool[AOF_R];
    unsigned short* Pl = &pool[AOF_P];
    int v = w * 16 + l15;                   // this lane's S column

    for (int jt = 0; jt < 24; ++jt) {
        int j0 = jt * 64;
        // ---- barrier A: K/RK for this step landed; prev-step readers done
        vmwait<0>();
        __builtin_amdgcn_s_barrier();
        __builtin_amdgcn_sched_barrier(0);
        stageV(j0);                          // 6 loads, hidden under content/rel/softmax

        // ---- content (S cols w*16+l15) + rel band (R cols w*32 .. +31)
        f32x4 acc1[2] = {};
        f32x4 acc2[2][2] = {};
#pragma unroll
        for (int kk = 0; kk < 2; kk++) {
            int ch = kk * 4 + lg;
            int krow = w * 16 + l15;
            bf16x8 kv = *(const bf16x8*)&pool[AOF_K + krow * 64 + swzo(krow, ch)];
#pragma unroll
            for (int m = 0; m < 2; m++)
                acc1[m] = __builtin_amdgcn_mfma_f32_16x16x32_bf16(qwf[m][kk], kv, acc1[m], 0, 0, 0);
#pragma unroll
            for (int n = 0; n < 2; n++) {
                int rrow = w * 32 + n * 16 + l15;
                bf16x8 rv = *(const bf16x8*)&pool[AOF_RK + rrow * 64 + swzo(rrow, ch)];
#pragma unroll
                for (int m = 0; m < 2; m++)
                    acc2[m][n] = __builtin_amdgcn_mfma_f32_16x16x32_bf16(qrf[m][kk], rv, acc2[m][n], 0, 0, 0);
            }
        }
        // ---- write R band to LDS (bf16, chunk-swizzled)
#pragma unroll
        for (int m = 0; m < 2; m++)
#pragma unroll
            for (int n = 0; n < 2; n++)
#pragma unroll
                for (int r = 0; r < 4; r++) {
                    int u = m * 16 + lg * 4 + r;
                    int c = w * 32 + n * 16 + l15;
                    int off = (((c >> 3) ^ (u & 7)) << 3) + (c & 7);
                    Rl[u * 128 + off] = f2bf(acc2[m][n][r]);
                }
        lgkmwait0();
        __builtin_amdgcn_s_barrier();        // barrier B: R ready; K/RK reads done
        __builtin_amdgcn_sched_barrier(0);
        if (jt < 23) { stageK(j0 + 64); stageRK(j0 + 64); }   // prefetch next tile

        // ---- S = content + shifted rel; wave-local row max
        float s[2][4], pmax[2][4];
#pragma unroll
        for (int m = 0; m < 2; m++)
#pragma unroll
            for (int r = 0; r < 4; r++) {
                int u = m * 16 + lg * 4 + r;
                int c = 31 + v - u;          // in [0,94]
                int off = (((c >> 3) ^ (u & 7)) << 3) + (c & 7);
                s[m][r] = acc1[m][r] + bf2f(Rl[u * 128 + off]);
                pmax[m][r] = s[m][r];
            }
#pragma unroll
        for (int off = 8; off; off >>= 1)
#pragma unroll
            for (int m = 0; m < 2; m++)
#pragma unroll
                for (int r = 0; r < 4; r++)
                    pmax[m][r] = fmaxf(pmax[m][r], __shfl_xor(pmax[m][r], off));
        if (l15 == 0) {
#pragma unroll
            for (int m = 0; m < 2; m++)
#pragma unroll
                for (int r = 0; r < 4; r++)
                    redm[(m * 16 + lg * 4 + r) * 4 + w] = pmax[m][r];
        }
        lgkmwait0();
        __builtin_amdgcn_s_barrier();        // barrier C: max partials ready
        __builtin_amdgcn_sched_barrier(0);

        // ---- m_new, rescale O/l, P = exp(S - m_new), partial sums
        float scale[2][4], psum[2][4];
#pragma unroll
        for (int m = 0; m < 2; m++)
#pragma unroll
            for (int r = 0; r < 4; r++) {
                int u = m * 16 + lg * 4 + r;
                f32x4 mm = *(f32x4*)&redm[u * 4];
                float mt = fmaxf(fmaxf(mm[0], mm[1]), fmaxf(mm[2], mm[3]));
                float mn = fmaxf(m_run[m][r], mt);
                scale[m][r] = __expf(m_run[m][r] - mn);
                m_run[m][r] = mn;
                float p = __expf(s[m][r] - mn);
                psum[m][r] = p;
                int off = (((v >> 3) ^ (u & 7)) << 3) + (v & 7);
                Pl[u * 64 + off] = f2bf(p);
            }
#pragma unroll
        for (int m = 0; m < 2; m++) {
#pragma unroll
            for (int n = 0; n < 3; n++)
#pragma unroll
                for (int r = 0; r < 4; r++)
                    accO[m][n][r] *= scale[m][r];
#pragma unroll
            for (int r = 0; r < 4; r++) l_run[m][r] *= scale[m][r];
        }
#pragma unroll
        for (int off = 8; off; off >>= 1)
#pragma unroll
            for (int m = 0; m < 2; m++)
#pragma unroll
                for (int r = 0; r < 4; r++)
                    psum[m][r] += __shfl_xor(psum[m][r], off);
        if (l15 == 0) {
#pragma unroll
            for (int m = 0; m < 2; m++)
#pragma unroll
                for (int r = 0; r < 4; r++)
                    reds[(m * 16 + lg * 4 + r) * 4 + w] = psum[m][r];
        }
        if (jt < 23) vmwait<6>(); else vmwait<0>();   // V landed; next K/RK stay in flight
        lgkmwait0();
        __builtin_amdgcn_s_barrier();        // barrier D: P + sum partials + V ready
        __builtin_amdgcn_sched_barrier(0);

        // ---- l update + PV accumulate
#pragma unroll
        for (int m = 0; m < 2; m++)
#pragma unroll
            for (int r = 0; r < 4; r++) {
                int u = m * 16 + lg * 4 + r;
                f32x4 sm = *(f32x4*)&reds[u * 4];
                l_run[m][r] += sm[0] + sm[1] + sm[2] + sm[3];
            }
#pragma unroll
        for (int kk = 0; kk < 2; kk++) {
            int ch = kk * 4 + lg;
            bf16x8 pa[2];
#pragma unroll
            for (int m = 0; m < 2; m++) {
                int row = m * 16 + l15;
                pa[m] = *(const bf16x8*)&Pl[row * 64 + swzo(row, ch)];
            }
#pragma unroll
            for (int n = 0; n < 3; n++) {
                int vrow = w * 48 + n * 16 + l15;
                bf16x8 vv = *(const bf16x8*)&pool[AOF_V + vrow * 64 + swzo(vrow, ch)];
#pragma unroll
                for (int m = 0; m < 2; m++)
                    accO[m][n] = __builtin_amdgcn_mfma_f32_16x16x32_bf16(pa[m], vv, accO[m][n], 0, 0, 0);
            }
        }
    }

    // ---- epilogue: o = O / l
#pragma unroll
    for (int m = 0; m < 2; m++)
#pragma unroll
        for (int r = 0; r < 4; r++) {
            int row = i0 + m * 16 + lg * 4 + r;
            float inv = 1.f / l_run[m][r];
#pragma unroll
            for (int n = 0; n < 3; n++) {
                int col = h * VD + w * 48 + n * 16 + l15;
                ob[(size_t)row * 1536 + col] = f2bf(accO[m][n][r] * inv);
            }
        }
}

// ---------------- launcher ----------------
extern "C" void kernel_launch(void* const* d_in, const int* in_sizes, int n_in,
                              void* d_out, int out_size, void* d_ws, size_t ws_size,
                              hipStream_t stream)
{
    const float* x     = (const float*)d_in[0];
    const float* ln1_g = (const float*)d_in[1];
    const float* ln1_b = (const float*)d_in[2];
    const float* ln2_g = (const float*)d_in[3];
    const float* ln2_b = (const float*)d_in[4];
    const float* Wq    = (const float*)d_in[5];
    const float* Wk    = (const float*)d_in[6];
    const float* Wv    = (const float*)d_in[7];
    const float* Wr    = (const float*)d_in[8];
    const float* Wo    = (const float*)d_in[9];
    const float* bo    = (const float*)d_in[10];
    const float* rwb   = (const float*)d_in[11];
    const float* rrb   = (const float*)d_in[12];
    const float* W1    = (const float*)d_in[13];
    const float* b1    = (const float*)d_in[14];
    const float* W2    = (const float*)d_in[15];
    const float* b2    = (const float*)d_in[16];
    float* out = (float*)d_out;

    char* w8 = (char*)d_ws;
    unsigned short* xnb  = (unsigned short*)(w8 + 0);         // [1536][1536]
    unsigned short* qwb  = (unsigned short*)(w8 + 4718592);   // [1536][512]
    unsigned short* qrb  = (unsigned short*)(w8 + 6291456);   // [1536][512]
    unsigned short* kbb  = (unsigned short*)(w8 + 7864320);   // [1536][512]
    unsigned short* vTb  = (unsigned short*)(w8 + 9437184);   // [1536][1536] (= kbb + 1536*512)
    unsigned short* posb = (unsigned short*)(w8 + 14155776);  // [3072][192]
    unsigned short* rkb  = (unsigned short*)(w8 + 15335424);  // [3072][512]
    unsigned short* Pb   = (unsigned short*)(w8 + 18481152);  // now scratch (h1 reuse)
    unsigned short* ob   = (unsigned short*)(w8 + 56229888);  // [1536][1536]
    float*          yb   = (float*)        (w8 + 60948480);   // [1536][1536] f32
    unsigned short* WqkvT= (unsigned short*)(w8 + 70385664);  // [2560][1536]
    unsigned short* WrT  = (unsigned short*)(w8 + 78249984);  // [512][192]
    unsigned short* WoT  = (unsigned short*)(w8 + 78446592);  // [1536][1536]
    unsigned short* W1T  = (unsigned short*)(w8 + 83165184);  // [3072][1536]
    unsigned short* W2T  = (unsigned short*)(w8 + 92602368);  // [1536][3072]
    unsigned short* h1b  = Pb;    // h1 buffer
    unsigned short* ynb  = xnb;   // reuse after QKV

    // merged prep: weight conversions (bf16, transposed) + ln1 + pos
    WCP wp;
    wp.e[0] = { Wq, WqkvT,                       1536, 512,      0 };
    wp.e[1] = { Wk, WqkvT + (size_t)512 * 1536,  1536, 512,    768 };
    wp.e[2] = { Wv, WqkvT + (size_t)1024 * 1536, 1536, 1536,  1536 };
    wp.e[3] = { Wr, WrT,                          192, 512,   3840 };
    wp.e[4] = { Wo, WoT,                         1536, 1536,  3936 };
    wp.e[5] = { W1, W1T,                         1536, 3072,  6240 };
    wp.e[6] = { W2, W2T,                         3072, 1536, 10848 };
    prep_all<<<WCONV_BLKS + LN1_BLKS + POS_BLKS, 256, 0, stream>>>(
        wp, x, ln1_g, ln1_b, xnb, posb);

    // fused qkv: 64x128 tile (480 blocks ~2/CU), 2D XCD chunks
    gemm_bf16<64, 128><<<dim3(20, 24, 1), 256, 0, stream>>>(xnb, WqkvT, qwb, qrb, kbb,
        1536, 2560, 1536, 1536, 1536, 0, 0, 0, 0,
        0.125f, rwb, rrb, nullptr, 4, 0, 0, 2);

    // rk = pos @ Wr  [3071,512]
    gemm_bf16<64, 128><<<dim3(4, 48, 1), 256, 0, stream>>>(posb, WrT, rkb, nullptr, nullptr,
        3071, 512, 192, 192, 192, 512, 0, 0, 0,
        1.f, nullptr, nullptr, nullptr, 1, 0, 0, 2);

    // fused attention: logits + softmax + PV  (384 blocks, 2/CU)
    attn_flash<<<dim3(48, 8), 256, 0, stream>>>(qwb, qrb, kbb, rkb, vTb, ob);

    // y = o @ Wo + bo + x   (f32) : 64x64 tile (576 blocks ~2.25/CU)
    gemm_bf16<64, 64><<<dim3(24, 24, 1), 256, 0, stream>>>(ob, WoT, yb, nullptr, nullptr,
        1536, 1536, 1536, 1536, 1536, 1536, 0, 0, 0,
        1.f, bo, nullptr, x, 0, 0, 0, 2);

    ln_kernel<<<TT / 4, 256, 0, stream>>>(yb, ln2_g, ln2_b, ynb);

    // h1 = relu(yn @ W1 + b1) bf16 : 64x128 tile (576 blocks)
    gemm_bf16<64, 128><<<dim3(24, 24, 1), 256, 0, stream>>>(ynb, W1T, h1b, nullptr, nullptr,
        1536, 3072, 1536, 1536, 1536, 3072, 0, 0, 0,
        1.f, b1, nullptr, nullptr, 1, 1, 0, 2);

    // out = y + h1 @ W2 + b2   (f32) : 64x64 tile (576 blocks), XM=4 for L2 fit
    gemm_bf16<64, 64><<<dim3(24, 24, 1), 256, 0, stream>>>(h1b, W2T, out, nullptr, nullptr,
        1536, 1536, 3072, 3072, 3072, 1536, 0, 0, 0,
        1.f, b2, nullptr, yb, 0, 0, 0, 4);
}

// Round 8
// 209.263 us; speedup vs baseline: 1.2300x; 1.2300x over previous
//
#include <hip/hip_runtime.h>
#include <math.h>

#define TT 1536
#define CC 1536
#define NH 8
#define KD 64
#define VD 192
#define FD 192

typedef short bf16x8 __attribute__((ext_vector_type(8)));
typedef float f32x4 __attribute__((ext_vector_type(4)));

__device__ inline unsigned short f2bf(float x) {
    unsigned u = __float_as_uint(x);
    u += 0x7FFF + ((u >> 16) & 1);
    return (unsigned short)(u >> 16);
}
__device__ inline float bf2f(unsigned short b) {
    return __uint_as_float(((unsigned)b) << 16);
}
__device__ inline void gload16(const void* g, void* l) {
    __builtin_amdgcn_global_load_lds(
        (const __attribute__((address_space(1))) unsigned int*)g,
        (__attribute__((address_space(3))) unsigned int*)l, 16, 0, 0);
}
// 16B-chunk XOR swizzle within a 64-elem (128B) bf16 row: chunk' = chunk ^ (row&7)
__device__ inline int swzo(int row, int chunk) { return (chunk ^ (row & 7)) << 3; }

template<int N> __device__ inline void vmwait() {
    if constexpr (N == 0)      asm volatile("s_waitcnt vmcnt(0)" ::: "memory");
    else if constexpr (N == 4) asm volatile("s_waitcnt vmcnt(4)" ::: "memory");
    else if constexpr (N == 6) asm volatile("s_waitcnt vmcnt(6)" ::: "memory");
    else                       asm volatile("s_waitcnt vmcnt(8)" ::: "memory");
}

// ---------------- wave-per-row LayerNorm helper (f32 -> bf16) ----------------
// optional: oinit[row] = x[row] + add_b  (fused init for split-K atomics)
__device__ inline void ln_row(const float* __restrict__ x,
                              const float* __restrict__ g,
                              const float* __restrict__ b,
                              unsigned short* __restrict__ out,
                              int row, int lane,
                              const float* __restrict__ add_b,
                              float* __restrict__ oinit)
{
    const float* xr = x + (size_t)row * CC;
    unsigned short* orow = out + (size_t)row * CC;

    float4 V[6];
    float s = 0.f, ss = 0.f;
#pragma unroll
    for (int c = 0; c < 6; c++) {
        V[c] = *reinterpret_cast<const float4*>(&xr[c * 256 + lane * 4]);
        s  += V[c].x + V[c].y + V[c].z + V[c].w;
        ss += V[c].x * V[c].x + V[c].y * V[c].y + V[c].z * V[c].z + V[c].w * V[c].w;
    }
#pragma unroll
    for (int off = 32; off; off >>= 1) {
        s  += __shfl_xor(s, off);
        ss += __shfl_xor(ss, off);
    }
    float mean = s * (1.f / CC);
    float var  = ss * (1.f / CC) - mean * mean;
    float rstd = rsqrtf(fmaxf(var, 0.f) + 1e-3f);
#pragma unroll
    for (int c = 0; c < 6; c++) {
        float4 G = *reinterpret_cast<const float4*>(&g[c * 256 + lane * 4]);
        float4 B = *reinterpret_cast<const float4*>(&b[c * 256 + lane * 4]);
        ushort4 pk;
        pk.x = f2bf((V[c].x - mean) * rstd * G.x + B.x);
        pk.y = f2bf((V[c].y - mean) * rstd * G.y + B.y);
        pk.z = f2bf((V[c].z - mean) * rstd * G.z + B.z);
        pk.w = f2bf((V[c].w - mean) * rstd * G.w + B.w);
        *reinterpret_cast<ushort4*>(&orow[c * 256 + lane * 4]) = pk;
        if (oinit) {
            float4 A2 = *reinterpret_cast<const float4*>(&add_b[c * 256 + lane * 4]);
            float4 o;
            o.x = V[c].x + A2.x; o.y = V[c].y + A2.y;
            o.z = V[c].z + A2.z; o.w = V[c].w + A2.w;
            *reinterpret_cast<float4*>(&oinit[(size_t)row * CC + c * 256 + lane * 4]) = o;
        }
    }
}

// standalone ln (4 rows per block, 1 wave per row)
__global__ __launch_bounds__(256)
void ln_kernel(const float* __restrict__ x, const float* __restrict__ g,
               const float* __restrict__ b, unsigned short* __restrict__ out,
               const float* __restrict__ add_b, float* __restrict__ oinit)
{
    int wid = threadIdx.x >> 6, lane = threadIdx.x & 63;
    ln_row(x, g, b, out, blockIdx.x * 4 + wid, lane, add_b, oinit);
}

// ---------------- merged prep: weight convert (7 mats) + ln1 + pos -----------
struct WCD { const float* W; unsigned short* Wt; int Kw, Nw, t0; };
struct WCP { WCD e[7]; };
#define WCONV_BLKS 15456
#define LN1_BLKS   384
#define POS_BLKS   (2 * TT - 1)

__global__ __launch_bounds__(256)
void prep_all(WCP p, const float* __restrict__ x,
              const float* __restrict__ ln1_g, const float* __restrict__ ln1_b,
              unsigned short* __restrict__ xnb, unsigned short* __restrict__ pos)
{
    int bid = blockIdx.x;
    int tid = threadIdx.x;

    if (bid < WCONV_BLKS) {
        __shared__ float t[32][33];
        int i = 0;
#pragma unroll
        for (int j = 1; j < 7; j++) if (bid >= p.e[j].t0) i = j;
        const float* W = p.e[i].W;
        unsigned short* Wt = p.e[i].Wt;
        int Kw = p.e[i].Kw, Nw = p.e[i].Nw;
        int local = bid - p.e[i].t0;
        int tpx = Nw >> 5;
        int n0 = (local % tpx) * 32, k0 = (local / tpx) * 32;

        int r = tid >> 3, c4 = (tid & 7) * 4;
        float4 v = *reinterpret_cast<const float4*>(&W[(size_t)(k0 + r) * Nw + n0 + c4]);
        t[r][c4 + 0] = v.x; t[r][c4 + 1] = v.y; t[r][c4 + 2] = v.z; t[r][c4 + 3] = v.w;
        __syncthreads();
        ushort4 pk;
        pk.x = f2bf(t[c4 + 0][r]);
        pk.y = f2bf(t[c4 + 1][r]);
        pk.z = f2bf(t[c4 + 2][r]);
        pk.w = f2bf(t[c4 + 3][r]);
        *reinterpret_cast<ushort4*>(&Wt[(size_t)(n0 + r) * Kw + k0 + c4]) = pk;
        return;
    }

    if (bid < WCONV_BLKS + LN1_BLKS) {
        int grp = bid - WCONV_BLKS;
        int wid = tid >> 6, lane = tid & 63;
        ln_row(x, ln1_g, ln1_b, xnb, grp * 4 + wid, lane, nullptr, nullptr);
        return;
    }

    // positional features, one l per block
    {
        int l = bid - (WCONV_BLKS + LN1_BLKS);
        float pp = (float)(l - (TT - 1));
        float ap = fabsf(pp);
        float sgn = (pp > 0.f) ? 1.f : ((pp < 0.f) ? -1.f : 0.f);

        __shared__ float gp[32];
        __shared__ float gmax_s;
        if (tid < 32) {
            int j = tid;
            double conc = 4.0 * (double)(j + 1) * (double)(j + 1);
            double rate = (double)(j + 1) / 12.0;
            double log_norm = lgamma(conc) - conc * log(rate);
            double prob;
            if (ap == 0.f) prob = 1e-8;
            else prob = exp((conc - 1.0) * log((double)ap) - rate * (double)ap - log_norm) + 1e-8;
            gp[j] = (float)prob;
        }
        __syncthreads();
        if (tid == 0) {
            float m = gp[0];
            for (int j = 1; j < 32; j++) m = fmaxf(m, gp[j]);
            gmax_s = m;
        }
        __syncthreads();
        if (tid < 96) {
            int cls = tid / 32, j = tid % 32;
            float val;
            if (cls == 0) {
                double step = (10.584962500721156 - 3.0) / 31.0;
                double hl = exp2(3.0 + j * step);
                val = (float)exp(-(double)ap * 0.6931471805599453 / hl);
            } else if (cls == 1) {
                float width = exp2f((float)(j + 1)) - 1.f;
                val = (width > ap) ? 1.f : 0.f;
            } else {
                val = gp[j] / gmax_s;
            }
            pos[(size_t)l * FD + tid] = f2bf(val);
            pos[(size_t)l * FD + 96 + tid] = f2bf(sgn * val);
        }
    }
}

// ---------------- bf16 MFMA GEMM core, TMxTN tile, 4 waves ----------------
// 2-deep double buffer + counted vmcnt. Wave tile = (TM/2)x(TN/2).
// xm: 2 or 4 -> 2D XCD chunking; 0 -> linear XCD swizzle.
// mode 0: f32 out  mode 1: bf16 out  mode 4: fused qkv epilogue
// mode 5: split-K partial, f32 atomicAdd into pre-initialized C
// head_ndiv!=0: A += (n0/head_ndiv)*sA
template<int TM, int TN>
__device__ void gemm_core(const unsigned short* __restrict__ A,
                          const unsigned short* __restrict__ Bt,
                          void* __restrict__ Cv, unsigned short* __restrict__ C2,
                          unsigned short* __restrict__ C3,
                          int M, int N, int K, int lda, int ldb, int ldc,
                          long sA, long sB, long sC,
                          float alpha, const float* __restrict__ bias,
                          const float* __restrict__ bias2,
                          const float* __restrict__ resid,
                          int mode, int relu, int head_ndiv, int xm,
                          int gx, int gy, int d, int bz)
{
    constexpr int WM = TM / 2, WN = TN / 2;
    constexpr int MF = WM / 16, NF = WN / 16;
    constexpr int LPT = TM / 32 + TN / 32;       // per-thread loads per K-tile
    __shared__ unsigned short lA[2][TM * 64];
    __shared__ unsigned short lB[2][TN * 64];

    int tid = threadIdx.x;
    int w = tid >> 6, l = tid & 63;

    int bx, by;
    if (xm) {
        int xn = 8 / xm;
        int cm = gy / xm, cn = gx / xn;
        int xcd = d & 7, local = d >> 3;
        int bxl = local / cm, byl = local % cm;
        by = (xcd / xn) * cm + byl;
        bx = (xcd % xn) * cn + bxl;
    } else {
        int nwg = gx * gy;
        int work = d;
        if ((nwg & 7) == 0) work = (d & 7) * (nwg >> 3) + (d >> 3);
        bx = work % gx;
        by = work / gx;
    }

    int n0 = bx * TN;
    int m0 = by * TM;
    if (head_ndiv) {
        A += (size_t)(n0 / head_ndiv) * sA;
    } else {
        A  += (size_t)bz * sA;
        Bt += (size_t)bz * sB;
    }
    int R0 = (w & 1) * WM, C0 = (w >> 1) * WN;
    int lrow = l >> 3;
    int lsw = ((l & 7) ^ lrow) << 3;       // swizzled source chunk (elements)
    int l15 = l & 15, lg = l >> 4;

    f32x4 acc[MF][NF] = {};

    const int NSTEP = K >> 6;

    auto STAGE = [&](int t, int buf) {
        int k0 = t << 6;
#pragma unroll
        for (int q = 0; q < TM / 32; q++) {
            int r0 = w * (TM / 4) + q * 8;
            gload16(A + (size_t)(m0 + r0 + lrow) * lda + k0 + lsw, &lA[buf][r0 * 64]);
        }
#pragma unroll
        for (int q = 0; q < TN / 32; q++) {
            int r0 = w * (TN / 4) + q * 8;
            gload16(Bt + (size_t)(n0 + r0 + lrow) * ldb + k0 + lsw, &lB[buf][r0 * 64]);
        }
    };

    STAGE(0, 0);

    int cur = 0;
    for (int t = 0; t < NSTEP; ++t) {
        if (t + 1 < NSTEP) {
            STAGE(t + 1, cur ^ 1);     // buffer freed by barrier at end of t-1
            vmwait<LPT>();             // tile t complete; t+1 stays in flight
        } else {
            vmwait<0>();
        }
        __builtin_amdgcn_s_barrier();
        __builtin_amdgcn_sched_barrier(0);

#pragma unroll
        for (int kk = 0; kk < 2; kk++) {
            int ch = kk * 4 + lg;
            bf16x8 av[MF], bv[NF];
#pragma unroll
            for (int m = 0; m < MF; m++) {
                int row = R0 + m * 16 + l15;
                av[m] = *(const bf16x8*)&lA[cur][row * 64 + swzo(row, ch)];
            }
#pragma unroll
            for (int n = 0; n < NF; n++) {
                int row = C0 + n * 16 + l15;
                bv[n] = *(const bf16x8*)&lB[cur][row * 64 + swzo(row, ch)];
            }
#pragma unroll
            for (int m = 0; m < MF; m++)
#pragma unroll
                for (int n = 0; n < NF; n++)
                    acc[m][n] = __builtin_amdgcn_mfma_f32_16x16x32_bf16(av[m], bv[n], acc[m][n], 0, 0, 0);
        }
        __builtin_amdgcn_s_barrier();  // all waves done reading buf cur
        cur ^= 1;
    }

    int rb = m0 + R0 + lg * 4;
    int cb = n0 + C0 + l15;

    if (mode == 4) {
        unsigned short* qw = (unsigned short*)Cv;
#pragma unroll
        for (int m = 0; m < MF; m++) {
            int rowb = rb + m * 16;
#pragma unroll
            for (int n = 0; n < NF; n++) {
                int col = cb + n * 16;
                if (col < 512) {
#pragma unroll
                    for (int reg = 0; reg < 4; reg++) {
                        int row = rowb + reg;
                        float v = alpha * acc[m][n][reg];
                        qw[(size_t)row * 512 + col] = f2bf(v + bias[col]);
                        C2[(size_t)row * 512 + col] = f2bf(v + bias2[col]);
                    }
                } else if (col < 1024) {
                    unsigned short* kb = C3;
#pragma unroll
                    for (int reg = 0; reg < 4; reg++)
                        kb[(size_t)(rowb + reg) * 512 + col - 512] = f2bf(acc[m][n][reg]);
                } else {
                    unsigned short* vT = (unsigned short*)(void*)(C3 + (size_t)1536 * 512);
                    int vc = col - 1024;
                    ushort4 pk;
                    pk.x = f2bf(acc[m][n][0]);
                    pk.y = f2bf(acc[m][n][1]);
                    pk.z = f2bf(acc[m][n][2]);
                    pk.w = f2bf(acc[m][n][3]);
                    *reinterpret_cast<ushort4*>(&vT[(size_t)vc * 1536 + rowb]) = pk;
                }
            }
        }
        return;
    }

    if (mode == 5) {
        float* C = (float*)Cv;
#pragma unroll
        for (int m = 0; m < MF; m++) {
#pragma unroll
            for (int n = 0; n < NF; n++) {
                int col = cb + n * 16;
#pragma unroll
                for (int reg = 0; reg < 4; reg++) {
                    int row = rb + m * 16 + reg;
                    atomicAdd(&C[(size_t)row * ldc + col], alpha * acc[m][n][reg]);
                }
            }
        }
        return;
    }

#pragma unroll
    for (int m = 0; m < MF; m++) {
#pragma unroll
        for (int n = 0; n < NF; n++) {
            int col = cb + n * 16;
            if (col >= N) continue;
            float bs = bias ? bias[col] : 0.f;
#pragma unroll
            for (int reg = 0; reg < 4; reg++) {
                int row = rb + m * 16 + reg;
                if (row >= M) continue;
                float v = alpha * acc[m][n][reg] + bs;
                if (resid) v += resid[(size_t)row * ldc + col];
                if (relu)  v = fmaxf(v, 0.f);
                if (mode == 1) {
                    unsigned short* C = (unsigned short*)Cv + (size_t)bz * sC;
                    C[(size_t)row * ldc + col] = f2bf(v);
                } else {
                    float* C = (float*)Cv + (size_t)bz * sC;
                    C[(size_t)row * ldc + col] = v;
                }
            }
        }
    }
}

template<int TM, int TN>
__global__ __launch_bounds__(256)
void gemm_bf16(const unsigned short* __restrict__ A,
               const unsigned short* __restrict__ Bt,
               void* __restrict__ Cv, unsigned short* __restrict__ C2,
               unsigned short* __restrict__ C3,
               int M, int N, int K, int lda, int ldb, int ldc,
               long sA, long sB, long sC,
               float alpha, const float* __restrict__ bias,
               const float* __restrict__ bias2,
               const float* __restrict__ resid,
               int mode, int relu, int head_ndiv, int xm)
{
    int d = blockIdx.y * gridDim.x + blockIdx.x;
    gemm_core<TM, TN>(A, Bt, Cv, C2, C3, M, N, K, lda, ldb, ldc, sA, sB, sC,
                      alpha, bias, bias2, resid, mode, relu, head_ndiv, xm,
                      gridDim.x, gridDim.y, d, blockIdx.z);
}

// two independent <64,128> GEMMs in one launch (block-range dispatch)
struct GP {
    const unsigned short *A, *Bt;
    void* Cv; unsigned short *C2, *C3;
    int M, N, K, lda, ldb, ldc;
    long sA, sB, sC;
    float alpha;
    const float *bias, *bias2, *resid;
    int mode, relu, head_ndiv, xm, gx, gy;
};

__global__ __launch_bounds__(256)
void gemm_dual128(GP a, GP b, int nblk0)
{
    int bid = blockIdx.x;
    if (bid < nblk0) {
        gemm_core<64, 128>(a.A, a.Bt, a.Cv, a.C2, a.C3, a.M, a.N, a.K,
                           a.lda, a.ldb, a.ldc, a.sA, a.sB, a.sC, a.alpha,
                           a.bias, a.bias2, a.resid, a.mode, a.relu,
                           a.head_ndiv, a.xm, a.gx, a.gy, bid, 0);
    } else {
        gemm_core<64, 128>(b.A, b.Bt, b.Cv, b.C2, b.C3, b.M, b.N, b.K,
                           b.lda, b.ldb, b.ldc, b.sA, b.sB, b.sC, b.alpha,
                           b.bias, b.bias2, b.resid, b.mode, b.relu,
                           b.head_ndiv, b.xm, b.gx, b.gy, bid - nblk0, 0);
    }
}

// ---------------- MFMA logits: content + shifted rel -> bf16 [8,T,T] ----------
// 40 KB LDS (shift buffer aliased over lQw/lQr as bf16) -> 4 blocks/CU
__global__ __launch_bounds__(256)
void logits_mfma(const unsigned short* __restrict__ qw,
                 const unsigned short* __restrict__ qr,
                 const unsigned short* __restrict__ kmat,
                 const unsigned short* __restrict__ rk,
                 unsigned short* __restrict__ out)
{
    __shared__ unsigned short pool[3 * 64 * 64 + 128 * 64];
    unsigned short* lQw = pool;
    unsigned short* lQr = pool + 64 * 64;
    unsigned short* lK  = pool + 2 * 64 * 64;
    unsigned short* lR  = pool + 3 * 64 * 64;
    unsigned short* lC2 = pool;              // alias lQw+lQr: [64][128] bf16

    int j0 = blockIdx.x * 64;
    int i0 = blockIdx.y * 64;
    int h  = blockIdx.z;
    int tid = threadIdx.x;
    int w = tid >> 6, l = tid & 63;
    int lrow = l >> 3;
    int lsw = ((l & 7) ^ lrow) << 3;
    int l15 = l & 15, lg = l >> 4;
    int obase = j0 - i0 + 1472;

#pragma unroll
    for (int q = 0; q < 2; q++) {
        int r0 = w * 16 + q * 8;
        gload16(qw   + (size_t)(i0 + r0 + lrow) * (NH * KD) + h * KD + lsw, &lQw[r0 * 64]);
        gload16(qr   + (size_t)(i0 + r0 + lrow) * (NH * KD) + h * KD + lsw, &lQr[r0 * 64]);
        gload16(kmat + (size_t)(j0 + r0 + lrow) * (NH * KD) + h * KD + lsw, &lK [r0 * 64]);
    }
#pragma unroll
    for (int q = 0; q < 4; q++) {
        int r0 = w * 32 + q * 8;
        gload16(rk + (size_t)(obase + r0 + lrow) * (NH * KD) + h * KD + lsw, &lR[r0 * 64]);
    }
    __syncthreads();

    f32x4 acc1[4] = {};
    f32x4 acc2[8] = {};
#pragma unroll
    for (int kk = 0; kk < 2; kk++) {
        int ch = kk * 4 + lg;
        int qrow = 16 * w + l15;
        bf16x8 av  = *(const bf16x8*)&lQw[qrow * 64 + swzo(qrow, ch)];
        bf16x8 arv = *(const bf16x8*)&lQr[qrow * 64 + swzo(qrow, ch)];
#pragma unroll
        for (int n = 0; n < 4; n++) {
            int row = n * 16 + l15;
            bf16x8 bv = *(const bf16x8*)&lK[row * 64 + swzo(row, ch)];
            acc1[n] = __builtin_amdgcn_mfma_f32_16x16x32_bf16(av, bv, acc1[n], 0, 0, 0);
        }
#pragma unroll
        for (int n = 0; n < 8; n++) {
            int row = n * 16 + l15;
            bf16x8 rv = *(const bf16x8*)&lR[row * 64 + swzo(row, ch)];
            acc2[n] = __builtin_amdgcn_mfma_f32_16x16x32_bf16(arv, rv, acc2[n], 0, 0, 0);
        }
    }
    __syncthreads();          // all reads of lQw/lQr done before aliased writes

#pragma unroll
    for (int n = 0; n < 8; n++)
#pragma unroll
        for (int reg = 0; reg < 4; reg++)
            lC2[(16 * w + lg * 4 + reg) * 128 + n * 16 + l15] = f2bf(acc2[n][reg]);
    __syncthreads();

#pragma unroll
    for (int n = 0; n < 4; n++) {
#pragma unroll
        for (int reg = 0; reg < 4; reg++) {
            int u = 16 * w + lg * 4 + reg;
            int v = n * 16 + l15;
            float val = acc1[n][reg] + bf2f(lC2[u * 128 + 63 + v - u]);
            out[((size_t)h * TT + i0 + u) * TT + j0 + v] = f2bf(val);
        }
    }
}

// ---------------- Row softmax bf16 in-place, 1 wave per row ----------------
__global__ __launch_bounds__(256)
void softmax_bf16(unsigned short* __restrict__ P)
{
    int wid = threadIdx.x >> 6, lane = threadIdx.x & 63;
    size_t r = (size_t)blockIdx.x * 4 + wid;
    unsigned* row = (unsigned*)(P + r * TT);

    uint4 U[3];
    float v[24];
    float m = -1e30f;
#pragma unroll
    for (int c = 0; c < 3; c++) {
        U[c] = *reinterpret_cast<const uint4*>(&row[c * 256 + lane * 4]);
        const unsigned* pd = (const unsigned*)&U[c];
#pragma unroll
        for (int d = 0; d < 4; d++) {
            float lo = bf2f((unsigned short)(pd[d] & 0xFFFF));
            float hi = bf2f((unsigned short)(pd[d] >> 16));
            v[c * 8 + 2 * d]     = lo;
            v[c * 8 + 2 * d + 1] = hi;
            m = fmaxf(m, fmaxf(lo, hi));
        }
    }
#pragma unroll
    for (int off = 32; off; off >>= 1) m = fmaxf(m, __shfl_xor(m, off));
    float s = 0.f;
#pragma unroll
    for (int i = 0; i < 24; i++) { v[i] = __expf(v[i] - m); s += v[i]; }
#pragma unroll
    for (int off = 32; off; off >>= 1) s += __shfl_xor(s, off);
    float inv = 1.f / s;
#pragma unroll
    for (int c = 0; c < 3; c++) {
        unsigned* pd = (unsigned*)&U[c];
#pragma unroll
        for (int d = 0; d < 4; d++)
            pd[d] = (unsigned)f2bf(v[c * 8 + 2 * d] * inv)
                  | ((unsigned)f2bf(v[c * 8 + 2 * d + 1] * inv) << 16);
        *reinterpret_cast<uint4*>(&row[c * 256 + lane * 4]) = U[c];
    }
}

// ---------------- launcher ----------------
extern "C" void kernel_launch(void* const* d_in, const int* in_sizes, int n_in,
                              void* d_out, int out_size, void* d_ws, size_t ws_size,
                              hipStream_t stream)
{
    const float* x     = (const float*)d_in[0];
    const float* ln1_g = (const float*)d_in[1];
    const float* ln1_b = (const float*)d_in[2];
    const float* ln2_g = (const float*)d_in[3];
    const float* ln2_b = (const float*)d_in[4];
    const float* Wq    = (const float*)d_in[5];
    const float* Wk    = (const float*)d_in[6];
    const float* Wv    = (const float*)d_in[7];
    const float* Wr    = (const float*)d_in[8];
    const float* Wo    = (const float*)d_in[9];
    const float* bo    = (const float*)d_in[10];
    const float* rwb   = (const float*)d_in[11];
    const float* rrb   = (const float*)d_in[12];
    const float* W1    = (const float*)d_in[13];
    const float* b1    = (const float*)d_in[14];
    const float* W2    = (const float*)d_in[15];
    const float* b2    = (const float*)d_in[16];
    float* out = (float*)d_out;

    char* w8 = (char*)d_ws;
    unsigned short* xnb  = (unsigned short*)(w8 + 0);         // [1536][1536]
    unsigned short* qwb  = (unsigned short*)(w8 + 4718592);   // [1536][512]
    unsigned short* qrb  = (unsigned short*)(w8 + 6291456);   // [1536][512]
    unsigned short* kbb  = (unsigned short*)(w8 + 7864320);   // [1536][512]
    unsigned short* vTb  = (unsigned short*)(w8 + 9437184);   // [1536][1536] (= kbb + 1536*512)
    unsigned short* posb = (unsigned short*)(w8 + 14155776);  // [3072][192]
    unsigned short* rkb  = (unsigned short*)(w8 + 15335424);  // [3072][512]
    unsigned short* Pb   = (unsigned short*)(w8 + 18481152);  // [8][1536][1536]
    unsigned short* ob   = (unsigned short*)(w8 + 56229888);  // [1536][1536]
    float*          yb   = (float*)        (w8 + 60948480);   // [1536][1536] f32
    unsigned short* WqkvT= (unsigned short*)(w8 + 70385664);  // [2560][1536]
    unsigned short* WrT  = (unsigned short*)(w8 + 78249984);  // [512][192]
    unsigned short* WoT  = (unsigned short*)(w8 + 78446592);  // [1536][1536]
    unsigned short* W1T  = (unsigned short*)(w8 + 83165184);  // [3072][1536]
    unsigned short* W2T  = (unsigned short*)(w8 + 92602368);  // [1536][3072]
    unsigned short* h1b  = Pb;    // reuse after AV
    unsigned short* ynb  = xnb;   // reuse after QKV

    // merged prep: weight conversions (bf16, transposed) + ln1 + pos
    WCP wp;
    wp.e[0] = { Wq, WqkvT,                       1536, 512,      0 };
    wp.e[1] = { Wk, WqkvT + (size_t)512 * 1536,  1536, 512,    768 };
    wp.e[2] = { Wv, WqkvT + (size_t)1024 * 1536, 1536, 1536,  1536 };
    wp.e[3] = { Wr, WrT,                          192, 512,   3840 };
    wp.e[4] = { Wo, WoT,                         1536, 1536,  3936 };
    wp.e[5] = { W1, W1T,                         1536, 3072,  6240 };
    wp.e[6] = { W2, W2T,                         3072, 1536, 10848 };
    prep_all<<<WCONV_BLKS + LN1_BLKS + POS_BLKS, 256, 0, stream>>>(
        wp, x, ln1_g, ln1_b, xnb, posb);

    // merged launch: fused qkv (480 blocks, 2D XCD chunks) + rk (192 blocks)
    GP ga = { xnb, WqkvT, qwb, qrb, kbb,
              1536, 2560, 1536, 1536, 1536, 0,
              0, 0, 0,
              0.125f, rwb, rrb, nullptr,
              4, 0, 0, 2, 20, 24 };
    GP gb = { posb, WrT, rkb, nullptr, nullptr,
              3071, 512, 192, 192, 192, 512,
              0, 0, 0,
              1.f, nullptr, nullptr, nullptr,
              1, 0, 0, 2, 4, 48 };
    gemm_dual128<<<672, 256, 0, stream>>>(ga, gb, 480);

    // logits + softmax (in place, bf16)
    logits_mfma<<<dim3(24, 24, 8), 256, 0, stream>>>(qwb, qrb, kbb, rkb, Pb);
    softmax_bf16<<<NH * TT / 4, 256, 0, stream>>>(Pb);

    // o = P @ V : 64x64 tile (576 blocks), head from n0/192
    gemm_bf16<64, 64><<<dim3(24, 24, 1), 256, 0, stream>>>(Pb, vTb, ob, nullptr, nullptr,
        1536, 1536, 1536, 1536, 1536, 1536, (long)TT * TT, 0, 0,
        1.f, nullptr, nullptr, nullptr, 1, 0, VD, 2);

    // y = o @ Wo + bo + x   (f32) : 64x64 tile (576 blocks ~2.25/CU)
    gemm_bf16<64, 64><<<dim3(24, 24, 1), 256, 0, stream>>>(ob, WoT, yb, nullptr, nullptr,
        1536, 1536, 1536, 1536, 1536, 1536, 0, 0, 0,
        1.f, bo, nullptr, x, 0, 0, 0, 2);

    // ln2 + pre-init out = y + b2 for the split-K W2 atomics
    ln_kernel<<<TT / 4, 256, 0, stream>>>(yb, ln2_g, ln2_b, ynb, b2, out);

    // h1 = relu(yn @ W1 + b1) bf16 : 64x128 tile (576 blocks)
    gemm_bf16<64, 128><<<dim3(24, 24, 1), 256, 0, stream>>>(ynb, W1T, h1b, nullptr, nullptr,
        1536, 3072, 1536, 1536, 1536, 3072, 0, 0, 0,
        1.f, b1, nullptr, nullptr, 1, 1, 0, 2);

    // out += h1 @ W2 (split-K=2, 64x64 tiles, 1152 blocks = 4.5/CU, atomics)
    gemm_bf16<64, 64><<<dim3(24, 24, 2), 256, 0, stream>>>(h1b, W2T, out, nullptr, nullptr,
        1536, 1536, 1536, 3072, 3072, 1536, 1536, 1536, 0,
        1.f, nullptr, nullptr, nullptr, 5, 0, 0, 4);
}

// Round 9
// 202.404 us; speedup vs baseline: 1.2717x; 1.0339x over previous
//
#include <hip/hip_runtime.h>
#include <math.h>

#define TT 1536
#define CC 1536
#define NH 8
#define KD 64
#define VD 192
#define FD 192

typedef short bf16x8 __attribute__((ext_vector_type(8)));
typedef float f32x4 __attribute__((ext_vector_type(4)));

__device__ inline unsigned short f2bf(float x) {
    unsigned u = __float_as_uint(x);
    u += 0x7FFF + ((u >> 16) & 1);
    return (unsigned short)(u >> 16);
}
__device__ inline float bf2f(unsigned short b) {
    return __uint_as_float(((unsigned)b) << 16);
}
__device__ inline void gload16(const void* g, void* l) {
    __builtin_amdgcn_global_load_lds(
        (const __attribute__((address_space(1))) unsigned int*)g,
        (__attribute__((address_space(3))) unsigned int*)l, 16, 0, 0);
}
// 16B-chunk XOR swizzle within a 64-elem (128B) bf16 row: chunk' = chunk ^ (row&7)
__device__ inline int swzo(int row, int chunk) { return (chunk ^ (row & 7)) << 3; }

template<int N> __device__ inline void vmwait() {
    if constexpr (N == 0)      asm volatile("s_waitcnt vmcnt(0)" ::: "memory");
    else if constexpr (N == 4) asm volatile("s_waitcnt vmcnt(4)" ::: "memory");
    else if constexpr (N == 6) asm volatile("s_waitcnt vmcnt(6)" ::: "memory");
    else                       asm volatile("s_waitcnt vmcnt(8)" ::: "memory");
}

// ---------------- wave-per-row LayerNorm helper (f32 -> bf16) ----------------
__device__ inline void ln_row(const float* __restrict__ x,
                              const float* __restrict__ g,
                              const float* __restrict__ b,
                              unsigned short* __restrict__ out,
                              int row, int lane)
{
    const float* xr = x + (size_t)row * CC;
    unsigned short* orow = out + (size_t)row * CC;

    float4 V[6];
    float s = 0.f, ss = 0.f;
#pragma unroll
    for (int c = 0; c < 6; c++) {
        V[c] = *reinterpret_cast<const float4*>(&xr[c * 256 + lane * 4]);
        s  += V[c].x + V[c].y + V[c].z + V[c].w;
        ss += V[c].x * V[c].x + V[c].y * V[c].y + V[c].z * V[c].z + V[c].w * V[c].w;
    }
#pragma unroll
    for (int off = 32; off; off >>= 1) {
        s  += __shfl_xor(s, off);
        ss += __shfl_xor(ss, off);
    }
    float mean = s * (1.f / CC);
    float var  = ss * (1.f / CC) - mean * mean;
    float rstd = rsqrtf(fmaxf(var, 0.f) + 1e-3f);
#pragma unroll
    for (int c = 0; c < 6; c++) {
        float4 G = *reinterpret_cast<const float4*>(&g[c * 256 + lane * 4]);
        float4 B = *reinterpret_cast<const float4*>(&b[c * 256 + lane * 4]);
        ushort4 pk;
        pk.x = f2bf((V[c].x - mean) * rstd * G.x + B.x);
        pk.y = f2bf((V[c].y - mean) * rstd * G.y + B.y);
        pk.z = f2bf((V[c].z - mean) * rstd * G.z + B.z);
        pk.w = f2bf((V[c].w - mean) * rstd * G.w + B.w);
        *reinterpret_cast<ushort4*>(&orow[c * 256 + lane * 4]) = pk;
    }
}

// standalone ln (4 rows per block, 1 wave per row)
__global__ __launch_bounds__(256)
void ln_kernel(const float* __restrict__ x, const float* __restrict__ g,
               const float* __restrict__ b, unsigned short* __restrict__ out)
{
    int wid = threadIdx.x >> 6, lane = threadIdx.x & 63;
    ln_row(x, g, b, out, blockIdx.x * 4 + wid, lane);
}

// ---------------- merged prep: weight convert (7 mats) + ln1 + pos -----------
struct WCD { const float* W; unsigned short* Wt; int Kw, Nw, t0; };
struct WCP { WCD e[7]; };
#define WCONV_BLKS 15456
#define LN1_BLKS   384
#define POS_BLKS   (2 * TT - 1)

__global__ __launch_bounds__(256)
void prep_all(WCP p, const float* __restrict__ x,
              const float* __restrict__ ln1_g, const float* __restrict__ ln1_b,
              unsigned short* __restrict__ xnb, unsigned short* __restrict__ pos)
{
    int bid = blockIdx.x;
    int tid = threadIdx.x;

    if (bid < WCONV_BLKS) {
        __shared__ float t[32][33];
        int i = 0;
#pragma unroll
        for (int j = 1; j < 7; j++) if (bid >= p.e[j].t0) i = j;
        const float* W = p.e[i].W;
        unsigned short* Wt = p.e[i].Wt;
        int Kw = p.e[i].Kw, Nw = p.e[i].Nw;
        int local = bid - p.e[i].t0;
        int tpx = Nw >> 5;
        int n0 = (local % tpx) * 32, k0 = (local / tpx) * 32;

        int r = tid >> 3, c4 = (tid & 7) * 4;
        float4 v = *reinterpret_cast<const float4*>(&W[(size_t)(k0 + r) * Nw + n0 + c4]);
        t[r][c4 + 0] = v.x; t[r][c4 + 1] = v.y; t[r][c4 + 2] = v.z; t[r][c4 + 3] = v.w;
        __syncthreads();
        ushort4 pk;
        pk.x = f2bf(t[c4 + 0][r]);
        pk.y = f2bf(t[c4 + 1][r]);
        pk.z = f2bf(t[c4 + 2][r]);
        pk.w = f2bf(t[c4 + 3][r]);
        *reinterpret_cast<ushort4*>(&Wt[(size_t)(n0 + r) * Kw + k0 + c4]) = pk;
        return;
    }

    if (bid < WCONV_BLKS + LN1_BLKS) {
        int grp = bid - WCONV_BLKS;
        int wid = tid >> 6, lane = tid & 63;
        ln_row(x, ln1_g, ln1_b, xnb, grp * 4 + wid, lane);
        return;
    }

    // positional features, one l per block
    {
        int l = bid - (WCONV_BLKS + LN1_BLKS);
        float pp = (float)(l - (TT - 1));
        float ap = fabsf(pp);
        float sgn = (pp > 0.f) ? 1.f : ((pp < 0.f) ? -1.f : 0.f);

        __shared__ float gp[32];
        __shared__ float gmax_s;
        if (tid < 32) {
            int j = tid;
            double conc = 4.0 * (double)(j + 1) * (double)(j + 1);
            double rate = (double)(j + 1) / 12.0;
            double log_norm = lgamma(conc) - conc * log(rate);
            double prob;
            if (ap == 0.f) prob = 1e-8;
            else prob = exp((conc - 1.0) * log((double)ap) - rate * (double)ap - log_norm) + 1e-8;
            gp[j] = (float)prob;
        }
        __syncthreads();
        if (tid == 0) {
            float m = gp[0];
            for (int j = 1; j < 32; j++) m = fmaxf(m, gp[j]);
            gmax_s = m;
        }
        __syncthreads();
        if (tid < 96) {
            int cls = tid / 32, j = tid % 32;
            float val;
            if (cls == 0) {
                double step = (10.584962500721156 - 3.0) / 31.0;
                double hl = exp2(3.0 + j * step);
                val = (float)exp(-(double)ap * 0.6931471805599453 / hl);
            } else if (cls == 1) {
                float width = exp2f((float)(j + 1)) - 1.f;
                val = (width > ap) ? 1.f : 0.f;
            } else {
                val = gp[j] / gmax_s;
            }
            pos[(size_t)l * FD + tid] = f2bf(val);
            pos[(size_t)l * FD + 96 + tid] = f2bf(sgn * val);
        }
    }
}

// ---------------- bf16 MFMA GEMM core, TMxTN tile, 4 waves ----------------
// 2-deep double buffer + counted vmcnt. Wave tile = (TM/2)x(TN/2).
// xm: 2 or 4 -> 2D XCD chunking; 0 -> linear XCD swizzle.
// mode 0: f32 out  mode 1: bf16 out  mode 4: fused qkv epilogue
// head_ndiv!=0: A += (n0/head_ndiv)*sA
template<int TM, int TN>
__device__ void gemm_core(const unsigned short* __restrict__ A,
                          const unsigned short* __restrict__ Bt,
                          void* __restrict__ Cv, unsigned short* __restrict__ C2,
                          unsigned short* __restrict__ C3,
                          int M, int N, int K, int lda, int ldb, int ldc,
                          long sA, long sB, long sC,
                          float alpha, const float* __restrict__ bias,
                          const float* __restrict__ bias2,
                          const float* __restrict__ resid,
                          int mode, int relu, int head_ndiv, int xm,
                          int gx, int gy, int d, int bz)
{
    constexpr int WM = TM / 2, WN = TN / 2;
    constexpr int MF = WM / 16, NF = WN / 16;
    constexpr int LPT = TM / 32 + TN / 32;       // per-thread loads per K-tile
    __shared__ unsigned short lA[2][TM * 64];
    __shared__ unsigned short lB[2][TN * 64];

    int tid = threadIdx.x;
    int w = tid >> 6, l = tid & 63;

    int bx, by;
    if (xm) {
        int xn = 8 / xm;
        int cm = gy / xm, cn = gx / xn;
        int xcd = d & 7, local = d >> 3;
        int bxl = local / cm, byl = local % cm;
        by = (xcd / xn) * cm + byl;
        bx = (xcd % xn) * cn + bxl;
    } else {
        int nwg = gx * gy;
        int work = d;
        if ((nwg & 7) == 0) work = (d & 7) * (nwg >> 3) + (d >> 3);
        bx = work % gx;
        by = work / gx;
    }

    int n0 = bx * TN;
    int m0 = by * TM;
    if (head_ndiv) {
        A += (size_t)(n0 / head_ndiv) * sA;
    } else {
        A  += (size_t)bz * sA;
        Bt += (size_t)bz * sB;
    }
    int R0 = (w & 1) * WM, C0 = (w >> 1) * WN;
    int lrow = l >> 3;
    int lsw = ((l & 7) ^ lrow) << 3;       // swizzled source chunk (elements)
    int l15 = l & 15, lg = l >> 4;

    f32x4 acc[MF][NF] = {};

    const int NSTEP = K >> 6;

    auto STAGE = [&](int t, int buf) {
        int k0 = t << 6;
#pragma unroll
        for (int q = 0; q < TM / 32; q++) {
            int r0 = w * (TM / 4) + q * 8;
            gload16(A + (size_t)(m0 + r0 + lrow) * lda + k0 + lsw, &lA[buf][r0 * 64]);
        }
#pragma unroll
        for (int q = 0; q < TN / 32; q++) {
            int r0 = w * (TN / 4) + q * 8;
            gload16(Bt + (size_t)(n0 + r0 + lrow) * ldb + k0 + lsw, &lB[buf][r0 * 64]);
        }
    };

    STAGE(0, 0);

    int cur = 0;
    for (int t = 0; t < NSTEP; ++t) {
        if (t + 1 < NSTEP) {
            STAGE(t + 1, cur ^ 1);     // buffer freed by barrier at end of t-1
            vmwait<LPT>();             // tile t complete; t+1 stays in flight
        } else {
            vmwait<0>();
        }
        __builtin_amdgcn_s_barrier();
        __builtin_amdgcn_sched_barrier(0);

#pragma unroll
        for (int kk = 0; kk < 2; kk++) {
            int ch = kk * 4 + lg;
            bf16x8 av[MF], bv[NF];
#pragma unroll
            for (int m = 0; m < MF; m++) {
                int row = R0 + m * 16 + l15;
                av[m] = *(const bf16x8*)&lA[cur][row * 64 + swzo(row, ch)];
            }
#pragma unroll
            for (int n = 0; n < NF; n++) {
                int row = C0 + n * 16 + l15;
                bv[n] = *(const bf16x8*)&lB[cur][row * 64 + swzo(row, ch)];
            }
#pragma unroll
            for (int m = 0; m < MF; m++)
#pragma unroll
                for (int n = 0; n < NF; n++)
                    acc[m][n] = __builtin_amdgcn_mfma_f32_16x16x32_bf16(av[m], bv[n], acc[m][n], 0, 0, 0);
        }
        __builtin_amdgcn_s_barrier();  // all waves done reading buf cur
        cur ^= 1;
    }

    int rb = m0 + R0 + lg * 4;
    int cb = n0 + C0 + l15;

    if (mode == 4) {
        unsigned short* qw = (unsigned short*)Cv;
#pragma unroll
        for (int m = 0; m < MF; m++) {
            int rowb = rb + m * 16;
#pragma unroll
            for (int n = 0; n < NF; n++) {
                int col = cb + n * 16;
                if (col < 512) {
#pragma unroll
                    for (int reg = 0; reg < 4; reg++) {
                        int row = rowb + reg;
                        float v = alpha * acc[m][n][reg];
                        qw[(size_t)row * 512 + col] = f2bf(v + bias[col]);
                        C2[(size_t)row * 512 + col] = f2bf(v + bias2[col]);
                    }
                } else if (col < 1024) {
                    unsigned short* kb = C3;
#pragma unroll
                    for (int reg = 0; reg < 4; reg++)
                        kb[(size_t)(rowb + reg) * 512 + col - 512] = f2bf(acc[m][n][reg]);
                } else {
                    unsigned short* vT = (unsigned short*)(void*)(C3 + (size_t)1536 * 512);
                    int vc = col - 1024;
                    ushort4 pk;
                    pk.x = f2bf(acc[m][n][0]);
                    pk.y = f2bf(acc[m][n][1]);
                    pk.z = f2bf(acc[m][n][2]);
                    pk.w = f2bf(acc[m][n][3]);
                    *reinterpret_cast<ushort4*>(&vT[(size_t)vc * 1536 + rowb]) = pk;
                }
            }
        }
        return;
    }

#pragma unroll
    for (int m = 0; m < MF; m++) {
#pragma unroll
        for (int n = 0; n < NF; n++) {
            int col = cb + n * 16;
            if (col >= N) continue;
            float bs = bias ? bias[col] : 0.f;
#pragma unroll
            for (int reg = 0; reg < 4; reg++) {
                int row = rb + m * 16 + reg;
                if (row >= M) continue;
                float v = alpha * acc[m][n][reg] + bs;
                if (resid) v += resid[(size_t)row * ldc + col];
                if (relu)  v = fmaxf(v, 0.f);
                if (mode == 1) {
                    unsigned short* C = (unsigned short*)Cv + (size_t)bz * sC;
                    C[(size_t)row * ldc + col] = f2bf(v);
                } else {
                    float* C = (float*)Cv + (size_t)bz * sC;
                    C[(size_t)row * ldc + col] = v;
                }
            }
        }
    }
}

template<int TM, int TN>
__global__ __launch_bounds__(256)
void gemm_bf16(const unsigned short* __restrict__ A,
               const unsigned short* __restrict__ Bt,
               void* __restrict__ Cv, unsigned short* __restrict__ C2,
               unsigned short* __restrict__ C3,
               int M, int N, int K, int lda, int ldb, int ldc,
               long sA, long sB, long sC,
               float alpha, const float* __restrict__ bias,
               const float* __restrict__ bias2,
               const float* __restrict__ resid,
               int mode, int relu, int head_ndiv, int xm)
{
    int d = blockIdx.y * gridDim.x + blockIdx.x;
    gemm_core<TM, TN>(A, Bt, Cv, C2, C3, M, N, K, lda, ldb, ldc, sA, sB, sC,
                      alpha, bias, bias2, resid, mode, relu, head_ndiv, xm,
                      gridDim.x, gridDim.y, d, blockIdx.z);
}

// two independent <64,128> GEMMs in one launch (block-range dispatch)
struct GP {
    const unsigned short *A, *Bt;
    void* Cv; unsigned short *C2, *C3;
    int M, N, K, lda, ldb, ldc;
    long sA, sB, sC;
    float alpha;
    const float *bias, *bias2, *resid;
    int mode, relu, head_ndiv, xm, gx, gy;
};

__global__ __launch_bounds__(256)
void gemm_dual128(GP a, GP b, int nblk0)
{
    int bid = blockIdx.x;
    if (bid < nblk0) {
        gemm_core<64, 128>(a.A, a.Bt, a.Cv, a.C2, a.C3, a.M, a.N, a.K,
                           a.lda, a.ldb, a.ldc, a.sA, a.sB, a.sC, a.alpha,
                           a.bias, a.bias2, a.resid, a.mode, a.relu,
                           a.head_ndiv, a.xm, a.gx, a.gy, bid, 0);
    } else {
        gemm_core<64, 128>(b.A, b.Bt, b.Cv, b.C2, b.C3, b.M, b.N, b.K,
                           b.lda, b.ldb, b.ldc, b.sA, b.sB, b.sC, b.alpha,
                           b.bias, b.bias2, b.resid, b.mode, b.relu,
                           b.head_ndiv, b.xm, b.gx, b.gy, bid - nblk0, 0);
    }
}

// ---------------- MFMA logits: content + shifted rel -> bf16 [8,T,T] ----------
// 40 KB LDS (shift buffer aliased over lQw/lQr as bf16) -> 4 blocks/CU
__global__ __launch_bounds__(256)
void logits_mfma(const unsigned short* __restrict__ qw,
                 const unsigned short* __restrict__ qr,
                 const unsigned short* __restrict__ kmat,
                 const unsigned short* __restrict__ rk,
                 unsigned short* __restrict__ out)
{
    __shared__ unsigned short pool[3 * 64 * 64 + 128 * 64];
    unsigned short* lQw = pool;
    unsigned short* lQr = pool + 64 * 64;
    unsigned short* lK  = pool + 2 * 64 * 64;
    unsigned short* lR  = pool + 3 * 64 * 64;
    unsigned short* lC2 = pool;              // alias lQw+lQr: [64][128] bf16

    int j0 = blockIdx.x * 64;
    int i0 = blockIdx.y * 64;
    int h  = blockIdx.z;
    int tid = threadIdx.x;
    int w = tid >> 6, l = tid & 63;
    int lrow = l >> 3;
    int lsw = ((l & 7) ^ lrow) << 3;
    int l15 = l & 15, lg = l >> 4;
    int obase = j0 - i0 + 1472;

#pragma unroll
    for (int q = 0; q < 2; q++) {
        int r0 = w * 16 + q * 8;
        gload16(qw   + (size_t)(i0 + r0 + lrow) * (NH * KD) + h * KD + lsw, &lQw[r0 * 64]);
        gload16(qr   + (size_t)(i0 + r0 + lrow) * (NH * KD) + h * KD + lsw, &lQr[r0 * 64]);
        gload16(kmat + (size_t)(j0 + r0 + lrow) * (NH * KD) + h * KD + lsw, &lK [r0 * 64]);
    }
#pragma unroll
    for (int q = 0; q < 4; q++) {
        int r0 = w * 32 + q * 8;
        gload16(rk + (size_t)(obase + r0 + lrow) * (NH * KD) + h * KD + lsw, &lR[r0 * 64]);
    }
    __syncthreads();

    f32x4 acc1[4] = {};
    f32x4 acc2[8] = {};
#pragma unroll
    for (int kk = 0; kk < 2; kk++) {
        int ch = kk * 4 + lg;
        int qrow = 16 * w + l15;
        bf16x8 av  = *(const bf16x8*)&lQw[qrow * 64 + swzo(qrow, ch)];
        bf16x8 arv = *(const bf16x8*)&lQr[qrow * 64 + swzo(qrow, ch)];
#pragma unroll
        for (int n = 0; n < 4; n++) {
            int row = n * 16 + l15;
            bf16x8 bv = *(const bf16x8*)&lK[row * 64 + swzo(row, ch)];
            acc1[n] = __builtin_amdgcn_mfma_f32_16x16x32_bf16(av, bv, acc1[n], 0, 0, 0);
        }
#pragma unroll
        for (int n = 0; n < 8; n++) {
            int row = n * 16 + l15;
            bf16x8 rv = *(const bf16x8*)&lR[row * 64 + swzo(row, ch)];
            acc2[n] = __builtin_amdgcn_mfma_f32_16x16x32_bf16(arv, rv, acc2[n], 0, 0, 0);
        }
    }
    __syncthreads();          // all reads of lQw/lQr done before aliased writes

#pragma unroll
    for (int n = 0; n < 8; n++)
#pragma unroll
        for (int reg = 0; reg < 4; reg++)
            lC2[(16 * w + lg * 4 + reg) * 128 + n * 16 + l15] = f2bf(acc2[n][reg]);
    __syncthreads();

#pragma unroll
    for (int n = 0; n < 4; n++) {
#pragma unroll
        for (int reg = 0; reg < 4; reg++) {
            int u = 16 * w + lg * 4 + reg;
            int v = n * 16 + l15;
            float val = acc1[n][reg] + bf2f(lC2[u * 128 + 63 + v - u]);
            out[((size_t)h * TT + i0 + u) * TT + j0 + v] = f2bf(val);
        }
    }
}

// ---------------- Row softmax bf16 in-place, 1 wave per row ----------------
__global__ __launch_bounds__(256)
void softmax_bf16(unsigned short* __restrict__ P)
{
    int wid = threadIdx.x >> 6, lane = threadIdx.x & 63;
    size_t r = (size_t)blockIdx.x * 4 + wid;
    unsigned* row = (unsigned*)(P + r * TT);

    uint4 U[3];
    float v[24];
    float m = -1e30f;
#pragma unroll
    for (int c = 0; c < 3; c++) {
        U[c] = *reinterpret_cast<const uint4*>(&row[c * 256 + lane * 4]);
        const unsigned* pd = (const unsigned*)&U[c];
#pragma unroll
        for (int d = 0; d < 4; d++) {
            float lo = bf2f((unsigned short)(pd[d] & 0xFFFF));
            float hi = bf2f((unsigned short)(pd[d] >> 16));
            v[c * 8 + 2 * d]     = lo;
            v[c * 8 + 2 * d + 1] = hi;
            m = fmaxf(m, fmaxf(lo, hi));
        }
    }
#pragma unroll
    for (int off = 32; off; off >>= 1) m = fmaxf(m, __shfl_xor(m, off));
    float s = 0.f;
#pragma unroll
    for (int i = 0; i < 24; i++) { v[i] = __expf(v[i] - m); s += v[i]; }
#pragma unroll
    for (int off = 32; off; off >>= 1) s += __shfl_xor(s, off);
    float inv = 1.f / s;
#pragma unroll
    for (int c = 0; c < 3; c++) {
        unsigned* pd = (unsigned*)&U[c];
#pragma unroll
        for (int d = 0; d < 4; d++)
            pd[d] = (unsigned)f2bf(v[c * 8 + 2 * d] * inv)
                  | ((unsigned)f2bf(v[c * 8 + 2 * d + 1] * inv) << 16);
        *reinterpret_cast<uint4*>(&row[c * 256 + lane * 4]) = U[c];
    }
}

// ---------------- launcher ----------------
extern "C" void kernel_launch(void* const* d_in, const int* in_sizes, int n_in,
                              void* d_out, int out_size, void* d_ws, size_t ws_size,
                              hipStream_t stream)
{
    const float* x     = (const float*)d_in[0];
    const float* ln1_g = (const float*)d_in[1];
    const float* ln1_b = (const float*)d_in[2];
    const float* ln2_g = (const float*)d_in[3];
    const float* ln2_b = (const float*)d_in[4];
    const float* Wq    = (const float*)d_in[5];
    const float* Wk    = (const float*)d_in[6];
    const float* Wv    = (const float*)d_in[7];
    const float* Wr    = (const float*)d_in[8];
    const float* Wo    = (const float*)d_in[9];
    const float* bo    = (const float*)d_in[10];
    const float* rwb   = (const float*)d_in[11];
    const float* rrb   = (const float*)d_in[12];
    const float* W1    = (const float*)d_in[13];
    const float* b1    = (const float*)d_in[14];
    const float* W2    = (const float*)d_in[15];
    const float* b2    = (const float*)d_in[16];
    float* out = (float*)d_out;

    char* w8 = (char*)d_ws;
    unsigned short* xnb  = (unsigned short*)(w8 + 0);         // [1536][1536]
    unsigned short* qwb  = (unsigned short*)(w8 + 4718592);   // [1536][512]
    unsigned short* qrb  = (unsigned short*)(w8 + 6291456);   // [1536][512]
    unsigned short* kbb  = (unsigned short*)(w8 + 7864320);   // [1536][512]
    unsigned short* vTb  = (unsigned short*)(w8 + 9437184);   // [1536][1536] (= kbb + 1536*512)
    unsigned short* posb = (unsigned short*)(w8 + 14155776);  // [3072][192]
    unsigned short* rkb  = (unsigned short*)(w8 + 15335424);  // [3072][512]
    unsigned short* Pb   = (unsigned short*)(w8 + 18481152);  // [8][1536][1536]
    unsigned short* ob   = (unsigned short*)(w8 + 56229888);  // [1536][1536]
    float*          yb   = (float*)        (w8 + 60948480);   // [1536][1536] f32
    unsigned short* WqkvT= (unsigned short*)(w8 + 70385664);  // [2560][1536]
    unsigned short* WrT  = (unsigned short*)(w8 + 78249984);  // [512][192]
    unsigned short* WoT  = (unsigned short*)(w8 + 78446592);  // [1536][1536]
    unsigned short* W1T  = (unsigned short*)(w8 + 83165184);  // [3072][1536]
    unsigned short* W2T  = (unsigned short*)(w8 + 92602368);  // [1536][3072]
    unsigned short* h1b  = Pb;    // reuse after AV
    unsigned short* ynb  = xnb;   // reuse after QKV

    // merged prep: weight conversions (bf16, transposed) + ln1 + pos
    WCP wp;
    wp.e[0] = { Wq, WqkvT,                       1536, 512,      0 };
    wp.e[1] = { Wk, WqkvT + (size_t)512 * 1536,  1536, 512,    768 };
    wp.e[2] = { Wv, WqkvT + (size_t)1024 * 1536, 1536, 1536,  1536 };
    wp.e[3] = { Wr, WrT,                          192, 512,   3840 };
    wp.e[4] = { Wo, WoT,                         1536, 1536,  3936 };
    wp.e[5] = { W1, W1T,                         1536, 3072,  6240 };
    wp.e[6] = { W2, W2T,                         3072, 1536, 10848 };
    prep_all<<<WCONV_BLKS + LN1_BLKS + POS_BLKS, 256, 0, stream>>>(
        wp, x, ln1_g, ln1_b, xnb, posb);

    // merged launch: fused qkv (480 blocks, 2D XCD chunks) + rk (192 blocks)
    GP ga = { xnb, WqkvT, qwb, qrb, kbb,
              1536, 2560, 1536, 1536, 1536, 0,
              0, 0, 0,
              0.125f, rwb, rrb, nullptr,
              4, 0, 0, 2, 20, 24 };
    GP gb = { posb, WrT, rkb, nullptr, nullptr,
              3071, 512, 192, 192, 192, 512,
              0, 0, 0,
              1.f, nullptr, nullptr, nullptr,
              1, 0, 0, 2, 4, 48 };
    gemm_dual128<<<672, 256, 0, stream>>>(ga, gb, 480);

    // logits + softmax (in place, bf16)
    logits_mfma<<<dim3(24, 24, 8), 256, 0, stream>>>(qwb, qrb, kbb, rkb, Pb);
    softmax_bf16<<<NH * TT / 4, 256, 0, stream>>>(Pb);

    // o = P @ V : 64x64 tile (576 blocks), head from n0/192
    gemm_bf16<64, 64><<<dim3(24, 24, 1), 256, 0, stream>>>(Pb, vTb, ob, nullptr, nullptr,
        1536, 1536, 1536, 1536, 1536, 1536, (long)TT * TT, 0, 0,
        1.f, nullptr, nullptr, nullptr, 1, 0, VD, 2);

    // y = o @ Wo + bo + x   (f32) : 64x64 tile (576 blocks ~2.25/CU)
    gemm_bf16<64, 64><<<dim3(24, 24, 1), 256, 0, stream>>>(ob, WoT, yb, nullptr, nullptr,
        1536, 1536, 1536, 1536, 1536, 1536, 0, 0, 0,
        1.f, bo, nullptr, x, 0, 0, 0, 2);

    ln_kernel<<<TT / 4, 256, 0, stream>>>(yb, ln2_g, ln2_b, ynb);

    // h1 = relu(yn @ W1 + b1) bf16 : 64x128 tile (576 blocks)
    gemm_bf16<64, 128><<<dim3(24, 24, 1), 256, 0, stream>>>(ynb, W1T, h1b, nullptr, nullptr,
        1536, 3072, 1536, 1536, 1536, 3072, 0, 0, 0,
        1.f, b1, nullptr, nullptr, 1, 1, 0, 2);

    // out = y + h1 @ W2 + b2   (f32) : 64x64 tile (576 blocks), XM=4 for L2 fit
    gemm_bf16<64, 64><<<dim3(24, 24, 1), 256, 0, stream>>>(h1b, W2T, out, nullptr, nullptr,
        1536, 1536, 3072, 3072, 3072, 1536, 0, 0, 0,
        1.f, b2, nullptr, yb, 0, 0, 0, 4);
}